// Round 2
// baseline (163.894 us; speedup 1.0000x reference)
//
#include <hip/hip_runtime.h>
#include <math.h>

#define D_FEAT 64

// Edge-parallel CSR row-offset build. segment_ids is sorted; thread e fills
// starts[v] = e for every segment v that begins at edge e (covering gaps for
// empty segments). Covers starts[0..nN] exactly once across all threads.
__global__ void build_starts_kernel(const int* __restrict__ seg,
                                    int* __restrict__ starts,
                                    int nE, int nN) {
    int e = blockIdx.x * blockDim.x + threadIdx.x;
    if (e >= nE) return;
    int s = seg[e];
    int sprev = (e == 0) ? -1 : seg[e - 1];
    for (int v = sprev + 1; v <= s; ++v) starts[v] = e;
    if (e == nE - 1) {
        for (int v = s + 1; v <= nN; ++v) starts[v] = nE;
    }
}

__device__ __forceinline__ int lower_bound_dev(const int* __restrict__ seg,
                                               int nE, int val) {
    int lo = 0, hi = nE;
    while (lo < hi) {
        int mid = (lo + hi) >> 1;
        if (seg[mid] < val) lo = mid + 1; else hi = mid;
    }
    return lo;
}

// One wave (64 lanes) per node; lane d owns feature d. Each edge is one
// fully-coalesced 256B row load. Unroll-by-8 keeps 8 gathers in flight
// (avg segment = 16 edges -> ~2 dependent latency rounds per node).
template<bool USE_STARTS>
__global__ __launch_bounds__(256) void seg_max_kernel(
    const float* __restrict__ x, const int* __restrict__ nbr,
    const int* __restrict__ seg, const int* __restrict__ starts,
    float* __restrict__ out, int nE, int nN) {
    int wid  = blockIdx.x * (blockDim.x >> 6) + (threadIdx.x >> 6);
    int lane = threadIdx.x & 63;
    if (wid >= nN) return;

    int s, e;
    if (USE_STARTS) {
        s = starts[wid];
        e = starts[wid + 1];
    } else {
        s = lower_bound_dev(seg, nE, wid);
        e = lower_bound_dev(seg, nE, wid + 1);
    }

    float m = -INFINITY;
    int k = s;
    for (; k + 8 <= e; k += 8) {
        // Streamed edge indices: non-temporal (read-once), keep L2 for x.
        int j0 = __builtin_nontemporal_load(nbr + k + 0);
        int j1 = __builtin_nontemporal_load(nbr + k + 1);
        int j2 = __builtin_nontemporal_load(nbr + k + 2);
        int j3 = __builtin_nontemporal_load(nbr + k + 3);
        int j4 = __builtin_nontemporal_load(nbr + k + 4);
        int j5 = __builtin_nontemporal_load(nbr + k + 5);
        int j6 = __builtin_nontemporal_load(nbr + k + 6);
        int j7 = __builtin_nontemporal_load(nbr + k + 7);
        float a0 = x[j0 * D_FEAT + lane];
        float a1 = x[j1 * D_FEAT + lane];
        float a2 = x[j2 * D_FEAT + lane];
        float a3 = x[j3 * D_FEAT + lane];
        float a4 = x[j4 * D_FEAT + lane];
        float a5 = x[j5 * D_FEAT + lane];
        float a6 = x[j6 * D_FEAT + lane];
        float a7 = x[j7 * D_FEAT + lane];
        float t0 = fmaxf(fmaxf(a0, a1), fmaxf(a2, a3));
        float t1 = fmaxf(fmaxf(a4, a5), fmaxf(a6, a7));
        m = fmaxf(m, fmaxf(t0, t1));
    }
    for (; k < e; ++k) {
        int j = __builtin_nontemporal_load(nbr + k);
        m = fmaxf(m, x[j * D_FEAT + lane]);
    }

    // Write-once output: non-temporal store, don't evict x from L2.
    __builtin_nontemporal_store((e > s) ? m : 0.0f, out + wid * D_FEAT + lane);
}

extern "C" void kernel_launch(void* const* d_in, const int* in_sizes, int n_in,
                              void* d_out, int out_size, void* d_ws, size_t ws_size,
                              hipStream_t stream) {
    const float* x   = (const float*)d_in[0];
    const int*   nbr = (const int*)d_in[1];
    const int*   seg = (const int*)d_in[2];
    float*       out = (float*)d_out;

    int nN = in_sizes[0] / D_FEAT;  // 100000
    int nE = in_sizes[1];           // 1600000

    const int wavesPerBlock = 4;    // 256 threads
    int grid = (nN + wavesPerBlock - 1) / wavesPerBlock;

    size_t starts_bytes = (size_t)(nN + 1) * sizeof(int);
    if (ws_size >= starts_bytes) {
        int* starts = (int*)d_ws;
        int bgrid = (nE + 255) / 256;
        hipLaunchKernelGGL(build_starts_kernel, dim3(bgrid), dim3(256), 0, stream,
                           seg, starts, nE, nN);
        hipLaunchKernelGGL((seg_max_kernel<true>), dim3(grid), dim3(256), 0, stream,
                           x, nbr, seg, starts, out, nE, nN);
    } else {
        hipLaunchKernelGGL((seg_max_kernel<false>), dim3(grid), dim3(256), 0, stream,
                           x, nbr, seg, nullptr, out, nE, nN);
    }
}

// Round 4
// 139.712 us; speedup vs baseline: 1.1731x; 1.1731x over previous
//
#include <hip/hip_runtime.h>
#include <math.h>

#define D_FEAT 64

// Edge-parallel CSR row-offset build. segment_ids is sorted; thread e fills
// starts[v] = e for every segment v that begins at edge e (covering gaps for
// empty segments). Covers starts[0..nN] exactly once across all threads.
__global__ void build_starts_kernel(const int* __restrict__ seg,
                                    int* __restrict__ starts,
                                    int nE, int nN) {
    int e = blockIdx.x * blockDim.x + threadIdx.x;
    if (e >= nE) return;
    int s = seg[e];
    int sprev = (e == 0) ? -1 : seg[e - 1];
    for (int v = sprev + 1; v <= s; ++v) starts[v] = e;
    if (e == nE - 1) {
        for (int v = s + 1; v <= nN; ++v) starts[v] = nE;
    }
}

__device__ __forceinline__ int lower_bound_dev(const int* __restrict__ seg,
                                               int nE, int val) {
    int lo = 0, hi = nE;
    while (lo < hi) {
        int mid = (lo + hi) >> 1;
        if (seg[mid] < val) lo = mid + 1; else hi = mid;
    }
    return lo;
}

// One wave (64 lanes) per node; lane d owns feature d. Each edge is one
// fully-coalesced 256B row load.
//
// KEY: max is idempotent, so segments are padded to a multiple of 16 by
// clamping the edge index to e-1. Every round is 16 INDEPENDENT row loads
// (no serial remainder chain — the round-1 version's serial tail was a
// full-latency dependent chain and dominated). Duplicate clamped rows hit
// L1 (just fetched), costing only issue slots; VALU was 78% idle.
template<bool USE_STARTS>
__global__ __launch_bounds__(256) void seg_max_kernel(
    const float* __restrict__ x, const int* __restrict__ nbr,
    const int* __restrict__ seg, const int* __restrict__ starts,
    float* __restrict__ out, int nE, int nN) {
    int wid  = blockIdx.x * (blockDim.x >> 6) + (threadIdx.x >> 6);
    int lane = threadIdx.x & 63;
    if (wid >= nN) return;

    int s, e;
    if (USE_STARTS) {
        s = starts[wid];
        e = starts[wid + 1];
    } else {
        s = lower_bound_dev(seg, nE, wid);
        e = lower_bound_dev(seg, nE, wid + 1);
    }

    if (e <= s) {  // empty segment: zeros, don't touch nbr/x
        __builtin_nontemporal_store(0.0f, out + wid * D_FEAT + lane);
        return;
    }

    const float* xl = x + lane;
    const int eM1 = e - 1;
    float m = -INFINITY;

    for (int k = s; k < e; k += 16) {
        int   idx[16];
        float val[16];
#pragma unroll
        for (int j = 0; j < 16; ++j) {
            int kk = k + j;
            kk = (kk < eM1) ? kk : eM1;          // clamp: duplicates are free for max
            idx[j] = __builtin_nontemporal_load(nbr + kk);
        }
#pragma unroll
        for (int j = 0; j < 16; ++j) {
            val[j] = xl[idx[j] * D_FEAT];        // 16 independent 256B row loads
        }
#pragma unroll
        for (int j = 0; j < 16; ++j) {
            m = fmaxf(m, val[j]);
        }
    }

    // Write-once output: non-temporal store, don't evict x from L2.
    __builtin_nontemporal_store(m, out + wid * D_FEAT + lane);
}

extern "C" void kernel_launch(void* const* d_in, const int* in_sizes, int n_in,
                              void* d_out, int out_size, void* d_ws, size_t ws_size,
                              hipStream_t stream) {
    const float* x   = (const float*)d_in[0];
    const int*   nbr = (const int*)d_in[1];
    const int*   seg = (const int*)d_in[2];
    float*       out = (float*)d_out;

    int nN = in_sizes[0] / D_FEAT;  // 100000
    int nE = in_sizes[1];           // 1600000

    const int wavesPerBlock = 4;    // 256 threads
    int grid = (nN + wavesPerBlock - 1) / wavesPerBlock;

    size_t starts_bytes = (size_t)(nN + 1) * sizeof(int);
    if (ws_size >= starts_bytes) {
        int* starts = (int*)d_ws;
        int bgrid = (nE + 255) / 256;
        hipLaunchKernelGGL(build_starts_kernel, dim3(bgrid), dim3(256), 0, stream,
                           seg, starts, nE, nN);
        hipLaunchKernelGGL((seg_max_kernel<true>), dim3(grid), dim3(256), 0, stream,
                           x, nbr, seg, starts, out, nE, nN);
    } else {
        hipLaunchKernelGGL((seg_max_kernel<false>), dim3(grid), dim3(256), 0, stream,
                           x, nbr, seg, nullptr, out, nE, nN);
    }
}

// Round 5
// 132.971 us; speedup vs baseline: 1.2326x; 1.0507x over previous
//
#include <hip/hip_runtime.h>
#include <math.h>

#define D_FEAT 64

// Edge-parallel CSR row-offset build. segment_ids is sorted; thread e fills
// starts[v] = e for every segment v that begins at edge e (covering gaps for
// empty segments). Covers starts[0..nN] exactly once across all threads.
__global__ void build_starts_kernel(const int* __restrict__ seg,
                                    int* __restrict__ starts,
                                    int nE, int nN) {
    int e = blockIdx.x * blockDim.x + threadIdx.x;
    if (e >= nE) return;
    int s = seg[e];
    int sprev = (e == 0) ? -1 : seg[e - 1];
    for (int v = sprev + 1; v <= s; ++v) starts[v] = e;
    if (e == nE - 1) {
        for (int v = s + 1; v <= nN; ++v) starts[v] = nE;
    }
}

__device__ __forceinline__ int lower_bound_dev(const int* __restrict__ seg,
                                               int nE, int val) {
    int lo = 0, hi = nE;
    while (lo < hi) {
        int mid = (lo + hi) >> 1;
        if (seg[mid] < val) lo = mid + 1; else hi = mid;
    }
    return lo;
}

// One wave per node; lane d owns feature d (one coalesced 256B row load per
// edge). All control + row-base addressing is forced WAVE-UNIFORM:
//  - starts[] values go through readfirstlane -> s,e,k loop runs on SALU
//  - 64 edge indices are loaded coalesced (clamped to e-1; max is idempotent)
//    then extracted one-by-one via v_readlane(imm) -> row base is SGPR math,
//    gathers emit global_load saddr form (VALU per gather: just the fmax).
// Round-4 counters showed 28.7us of VALU-busy from per-lane address math +
// clamps; this moves that to the (idle) scalar pipe.
template<bool USE_STARTS>
__global__ __launch_bounds__(256) void seg_max_kernel(
    const float* __restrict__ x, const int* __restrict__ nbr,
    const int* __restrict__ seg, const int* __restrict__ starts,
    float* __restrict__ out, int nE, int nN) {
    int wid  = blockIdx.x * (blockDim.x >> 6) + (threadIdx.x >> 6);
    int lane = threadIdx.x & 63;
    if (wid >= nN) return;

    int s, e;
    if (USE_STARTS) {
        s = __builtin_amdgcn_readfirstlane(starts[wid]);
        e = __builtin_amdgcn_readfirstlane(starts[wid + 1]);
    } else {
        s = __builtin_amdgcn_readfirstlane(lower_bound_dev(seg, nE, wid));
        e = __builtin_amdgcn_readfirstlane(lower_bound_dev(seg, nE, wid + 1));
    }

    if (e <= s) {  // empty segment: zeros, don't touch nbr/x
        __builtin_nontemporal_store(0.0f, out + wid * D_FEAT + lane);
        return;
    }

    const float* __restrict__ xl = x + lane;
    const int eM1 = e - 1;
    float m = -INFINITY;

    for (int k = s; k < e; k += 64) {
        // One coalesced load of up to 64 edge indices, clamped to e-1
        // (duplicates are free for max; clamped tail rows hit L1).
        int kc = k + lane;
        kc = (kc < eM1) ? kc : eM1;
        int idxv = __builtin_nontemporal_load(nbr + kc);

#pragma unroll
        for (int j0 = 0; j0 < 64; j0 += 16) {
            if (k + j0 < e) {          // uniform (SALU) guard per 16-gather round
                float val[16];
#pragma unroll
                for (int j = 0; j < 16; ++j) {
                    // SGPR row index -> uniform base + lane offset = saddr load
                    int rj = __builtin_amdgcn_readlane(idxv, j0 + j);
                    const float* __restrict__ row = x + ((size_t)rj << 6);
                    val[j] = row[lane];
                }
                float t0 = fmaxf(fmaxf(val[0], val[1]), fmaxf(val[2], val[3]));
                float t1 = fmaxf(fmaxf(val[4], val[5]), fmaxf(val[6], val[7]));
                float t2 = fmaxf(fmaxf(val[8], val[9]), fmaxf(val[10], val[11]));
                float t3 = fmaxf(fmaxf(val[12], val[13]), fmaxf(val[14], val[15]));
                m = fmaxf(m, fmaxf(fmaxf(t0, t1), fmaxf(t2, t3)));
            }
        }
    }

    // Write-once output: non-temporal store, don't evict x from L2.
    __builtin_nontemporal_store(m, out + wid * D_FEAT + lane);
    (void)xl;
}

extern "C" void kernel_launch(void* const* d_in, const int* in_sizes, int n_in,
                              void* d_out, int out_size, void* d_ws, size_t ws_size,
                              hipStream_t stream) {
    const float* x   = (const float*)d_in[0];
    const int*   nbr = (const int*)d_in[1];
    const int*   seg = (const int*)d_in[2];
    float*       out = (float*)d_out;

    int nN = in_sizes[0] / D_FEAT;  // 100000
    int nE = in_sizes[1];           // 1600000

    const int wavesPerBlock = 4;    // 256 threads
    int grid = (nN + wavesPerBlock - 1) / wavesPerBlock;

    size_t starts_bytes = (size_t)(nN + 1) * sizeof(int);
    if (ws_size >= starts_bytes) {
        int* starts = (int*)d_ws;
        int bgrid = (nE + 255) / 256;
        hipLaunchKernelGGL(build_starts_kernel, dim3(bgrid), dim3(256), 0, stream,
                           seg, starts, nE, nN);
        hipLaunchKernelGGL((seg_max_kernel<true>), dim3(grid), dim3(256), 0, stream,
                           x, nbr, seg, starts, out, nE, nN);
    } else {
        hipLaunchKernelGGL((seg_max_kernel<false>), dim3(grid), dim3(256), 0, stream,
                           x, nbr, seg, nullptr, out, nE, nN);
    }
}